// Round 11
// baseline (733.481 us; speedup 1.0000x reference)
//
#include <hip/hip_runtime.h>
#include <stdint.h>

#define NB 4
#define NS 2048
#define NH 16
#define HSZ 64
#define ND 1024
#define NM (NB*NS)
// exp(x) = exp2(x*log2e); fold 1/sqrt(64)*log2e into Q scale
#define QSCALE 0.180336880f
// mask addend in exp2 domain: -10000*log2e; exp2(a+MADD2) underflows to exact 0
#define MADD2 -14426.950409f

typedef unsigned short u16;
typedef unsigned int u32;
typedef __attribute__((ext_vector_type(4))) float f32x4;
typedef __attribute__((ext_vector_type(8))) __bf16 bf16x8;

static __device__ __forceinline__ u16 f2bf(float f){
  unsigned int x = __builtin_bit_cast(unsigned int, f);
  x += 0x7fffu + ((x >> 16) & 1u);
  return (u16)(x >> 16);
}
// truncating round (P values in [0,1]; <=1ulp error, saves 3 VALU)
static __device__ __forceinline__ u16 f2bf_rz(float f){
  return (u16)(__builtin_bit_cast(unsigned int, f) >> 16);
}

#define GLDS16(gp, lp) __builtin_amdgcn_global_load_lds( \
    (const __attribute__((address_space(1))) void*)(gp),  \
    (__attribute__((address_space(3))) void*)(lp), 16, 0, 0)

// ---------------- cast f32 -> bf16, 4 elems/thread ----------------
__global__ __launch_bounds__(256) void k_cast(const float4* __restrict__ in,
                                              ushort4* __restrict__ out, int n4){
  int i = blockIdx.x*256 + threadIdx.x;
  if (i >= n4) return;
  float4 v = in[i];
  ushort4 o;
  o.x = f2bf(v.x); o.y = f2bf(v.y); o.z = f2bf(v.z); o.w = f2bf(v.w);
  out[i] = o;
}

// --- transpose+cast 1024x1024 x4: wq,wk,wv -> wcat (concat), wd -> wdt ---
__global__ __launch_bounds__(256) void k_transpose4(const float* __restrict__ wq,
    const float* __restrict__ wk, const float* __restrict__ wv,
    const float* __restrict__ wd, u16* __restrict__ wcat, u16* __restrict__ wdt){
  __shared__ float t[32][33];
  const int z = blockIdx.z;
  const float* in = (z==0) ? wq : (z==1) ? wk : (z==2) ? wv : wd;
  u16* out = (z<3) ? (wcat + (size_t)z*ND*ND) : wdt;
  int tx = threadIdx.x & 31, ty = threadIdx.x >> 5;
  int n0 = blockIdx.x*32, k0 = blockIdx.y*32;
  #pragma unroll
  for (int i=0;i<32;i+=8)
    t[ty+i][tx] = in[(size_t)(k0+ty+i)*ND + n0 + tx];
  __syncthreads();
  #pragma unroll
  for (int i=0;i<32;i+=8)
    out[(size_t)(n0+ty+i)*ND + k0 + tx] = f2bf(t[tx][ty+i]);
}

// ---------------- bf16 GEMM core: C[M=8192][N] = A[M][1024] @ Bt[N][1024]^T ----------------
// EPI 0: fused QKV (N=3072): sec 0 -> Q bf16 [B][H][S][64] scaled by QSCALE;
//        sec 1 -> K bf16 same layout; sec 2 -> V^T bf16 [B][H][64][S]
// EPI 2: dense (N=1024): out f32 [M][N] = acc + bias + resid
template<int EPI>
__global__ __launch_bounds__(256,2) void k_gemm(const u16* __restrict__ A,
    const u16* __restrict__ Bt, const float* __restrict__ b0,
    const float* __restrict__ b1, const float* __restrict__ b2,
    const float* __restrict__ resid, u16* __restrict__ Qo, u16* __restrict__ Ko,
    u16* __restrict__ Vto, float* __restrict__ Out){
  __shared__ u16 sA[128*64];
  __shared__ u16 sB[128*64];
  const int tid = threadIdx.x;
  const int wave = tid >> 6, lane = tid & 63;
  const int l15 = lane & 15, l4 = lane >> 4;
  const int m0 = blockIdx.x * 128, n0 = blockIdx.y * 128;
  const int wm = wave >> 1, wn = wave & 1;
  const f32x4 vz = {0.f,0.f,0.f,0.f};
  f32x4 acc[4][4];
  #pragma unroll
  for (int i=0;i<4;i++)
    #pragma unroll
    for (int j=0;j<4;j++) acc[i][j] = vz;

  for (int k0 = 0; k0 < 1024; k0 += 64){
    __syncthreads();
    #pragma unroll
    for (int t=0; t<4; t++){
      const int jb = (t*4 + wave)*64;
      const int j  = jb + lane;
      const int r = j >> 3, c = (j & 7) << 3;
      GLDS16(A  + (((size_t)(m0 + r)) << 10) + (size_t)(k0 + c), sA + jb*8);
      GLDS16(Bt + (((size_t)(n0 + r)) << 10) + (size_t)(k0 + c), sB + jb*8);
    }
    __syncthreads();
    #pragma unroll
    for (int kk=0; kk<64; kk+=32){
      bf16x8 af[4], bv[4];
      #pragma unroll
      for (int mi=0;mi<4;mi++)
        af[mi] = *(const bf16x8*)(const void*)(sA + (wm*64 + mi*16 + l15)*64 + kk + l4*8);
      #pragma unroll
      for (int ni=0;ni<4;ni++)
        bv[ni] = *(const bf16x8*)(const void*)(sB + (wn*64 + ni*16 + l15)*64 + kk + l4*8);
      #pragma unroll
      for (int mi=0;mi<4;mi++)
        #pragma unroll
        for (int ni=0;ni<4;ni++)
          acc[mi][ni] = __builtin_amdgcn_mfma_f32_16x16x32_bf16(af[mi], bv[ni], acc[mi][ni], 0, 0, 0);
    }
  }

  if (EPI == 0){
    const int sec = n0 >> 10;                       // block-uniform
    const float* bias = (sec==0) ? b0 : (sec==1) ? b1 : b2;
    const float scale = (sec==0) ? QSCALE : 1.0f;
    u16* dst = (sec==0) ? Qo : (sec==1) ? Ko : Vto;
    #pragma unroll
    for (int mi=0;mi<4;mi++){
      #pragma unroll
      for (int ni=0;ni<4;ni++){
        const int n = n0 + wn*64 + ni*16 + l15;
        const int nn = n & (ND-1);
        const int h = nn >> 6, d = nn & 63;
        const float bvv = bias[nn];
        #pragma unroll
        for (int j=0;j<4;j++){
          const int m = m0 + wm*64 + mi*16 + l4*4 + j;
          const int b = m >> 11, s = m & (NS-1);
          const float v = (acc[mi][ni][j] + bvv) * scale;
          if (sec < 2)
            dst[((((size_t)b*NH + h)*NS + s) << 6) + d] = f2bf(v);
          else
            dst[((((size_t)b*NH + h)*HSZ + d) << 11) + s] = f2bf(v);
        }
      }
    }
  } else {
    #pragma unroll
    for (int mi=0;mi<4;mi++){
      #pragma unroll
      for (int ni=0;ni<4;ni++){
        const int n = n0 + wn*64 + ni*16 + l15;
        const float bvv = b0[n];
        #pragma unroll
        for (int j=0;j<4;j++){
          const int m = m0 + wm*64 + mi*16 + l4*4 + j;
          const size_t o = ((size_t)m << 10) + n;
          Out[o] = acc[mi][ni][j] + bvv + resid[o];
        }
      }
    }
  }
}

// XCD-aware decode, pv grid (1024 blocks): bid = x + 8*(qb + 16*ghi)
static __device__ __forceinline__ void attn_decode(int bid, int& qb, int& bh){
  const int x = bid & 7, t = bid >> 3;
  qb = t & 15;
  bh = (t >> 4) * 8 + x;
}
// XCD-aware decode, stats grid (512 blocks, qb in 0..7): bid = x + 8*(qb + 8*ghi)
static __device__ __forceinline__ void attn_decode8(int bid, int& qb, int& bh){
  const int x = bid & 7, t = bid >> 3;
  qb = t & 7;
  bh = (t >> 3) * 8 + x;
}

// ------- attention pass 1: per-row 1/sum(exp2(s')) (fixed max = 0) -------
// 512 threads, 8 waves, 256 q-rows per block (wave owns 32 rows = 2 subtiles).
// No LDS staging: K panels are L2-resident (256 KB, XCD-swizzled); each wave
// loads K fragments directly global->reg (coalesced 2KB/wave segments).
// Barrier-free main loop.
__global__ __launch_bounds__(512,4) void k_attn_stats(const u16* __restrict__ Q,
    const u16* __restrict__ K, const int* __restrict__ mask,
    float* __restrict__ stats){
  __shared__ float sMadd[NS];
  const int tid = threadIdx.x, wave = tid>>6, lane = tid&63;
  const int l15 = lane&15, l4 = lane>>4;
  int qb, bh; attn_decode8(blockIdx.x, qb, bh);
  const int b = bh >> 4;
  const size_t hoff = (size_t)bh * NS * HSZ;
  const int q0 = qb*256 + wave*32;
  const u16* Kg = K + hoff;
  bf16x8 qf0[2], qf1[2];
  #pragma unroll
  for (int m=0;m<2;m++){
    qf0[m] = *(const bf16x8*)(const void*)(Q + hoff + (size_t)(q0+m*16+l15)*HSZ + l4*8);
    qf1[m] = *(const bf16x8*)(const void*)(Q + hoff + (size_t)(q0+m*16+l15)*HSZ + 32 + l4*8);
  }
  const f32x4 vz = {0.f,0.f,0.f,0.f};
  float lr[2][4] = {{0.f,0.f,0.f,0.f},{0.f,0.f,0.f,0.f}};

  #pragma unroll
  for (int t=0;t<4;t++){
    const int kk = t*512 + tid;
    sMadd[kk] = mask[b*NS + kk] ? MADD2 : 0.f;
  }
  __syncthreads();

  for (int kb=0; kb<NS; kb+=64){
    bf16x8 kf[4][2];
    #pragma unroll
    for (int n=0;n<4;n++){
      const u16* kp = Kg + (size_t)(kb + n*16 + l15)*HSZ + l4*8;
      kf[n][0] = *(const bf16x8*)(const void*)(kp);
      kf[n][1] = *(const bf16x8*)(const void*)(kp + 32);
    }
    #pragma unroll
    for (int n=0;n<4;n++){
      const float madd = sMadd[kb + n*16 + l15];
      #pragma unroll
      for (int m=0;m<2;m++){
        f32x4 a = vz;
        a = __builtin_amdgcn_mfma_f32_16x16x32_bf16(qf0[m], kf[n][0], a, 0,0,0);
        a = __builtin_amdgcn_mfma_f32_16x16x32_bf16(qf1[m], kf[n][1], a, 0,0,0);
        #pragma unroll
        for (int j=0;j<4;j++)
          lr[m][j] += __builtin_amdgcn_exp2f(a[j] + madd);
      }
    }
  }
  #pragma unroll
  for (int m=0;m<2;m++)
    #pragma unroll
    for (int j=0;j<4;j++){
      float l = lr[m][j];
      #pragma unroll
      for (int off=1; off<16; off<<=1)
        l += __shfl_xor(l, off, 64);
      if (l15 == 0)
        stats[(size_t)bh*NS + q0 + m*16 + l4*4 + j] = 1.f/l;
    }
}

// --------- attention pass 2: recompute scores, write attn f32, ctx = P@V ---------
// 512 threads, 8 waves, 128 q-rows per block. No LDS K/V staging (L2-resident
// panels, direct global->reg fragment loads); sP same-wave produce/consume;
// barrier-free main loop.
__global__ __launch_bounds__(512,4) void k_attn_pv(const u16* __restrict__ Q,
    const u16* __restrict__ K, const u16* __restrict__ Vt,
    const int* __restrict__ mask, const float* __restrict__ stats,
    float* __restrict__ attn, u16* __restrict__ ctx){
  __shared__ u16 sP[8][16][72];
  __shared__ float sMadd[NS];
  const int tid = threadIdx.x, wave = tid>>6, lane = tid&63;
  const int l15 = lane&15, l4 = lane>>4;
  int qb, bh; attn_decode(blockIdx.x, qb, bh);
  const int b = bh >> 4, h = bh & 15;
  const size_t hoff = (size_t)bh * NS * HSZ;
  const int q0 = qb*128 + wave*16;
  const u16* Kg = K + hoff;
  const u16* Vg = Vt + hoff;
  const bf16x8 qf0 = *(const bf16x8*)(const void*)(Q + hoff + (size_t)(q0+l15)*HSZ + l4*8);
  const bf16x8 qf1 = *(const bf16x8*)(const void*)(Q + hoff + (size_t)(q0+l15)*HSZ + 32 + l4*8);
  float rinv[4];
  #pragma unroll
  for (int j=0;j<4;j++)
    rinv[j] = stats[(size_t)bh*NS + q0 + l4*4 + j];
  const f32x4 vz = {0.f,0.f,0.f,0.f};
  f32x4 cacc[4];
  #pragma unroll
  for (int i=0;i<4;i++) cacc[i] = vz;
  float* attn_base = attn + (size_t)bh * NS * NS;

  #pragma unroll
  for (int t=0;t<4;t++){
    const int kk = t*512 + tid;
    sMadd[kk] = mask[b*NS + kk] ? MADD2 : 0.f;
  }
  __syncthreads();

  for (int kb=0; kb<NS; kb+=64){
    // K fragments direct from global (L2-hot)
    bf16x8 kf[4][2];
    #pragma unroll
    for (int n=0;n<4;n++){
      const u16* kp = Kg + (size_t)(kb + n*16 + l15)*HSZ + l4*8;
      kf[n][0] = *(const bf16x8*)(const void*)(kp);
      kf[n][1] = *(const bf16x8*)(const void*)(kp + 32);
    }
    #pragma unroll
    for (int n=0;n<4;n++){
      f32x4 a = vz;
      a = __builtin_amdgcn_mfma_f32_16x16x32_bf16(qf0, kf[n][0], a, 0,0,0);
      a = __builtin_amdgcn_mfma_f32_16x16x32_bf16(qf1, kf[n][1], a, 0,0,0);
      const float madd = sMadd[kb + n*16 + l15];
      #pragma unroll
      for (int j=0;j<4;j++){
        const float e = __builtin_amdgcn_exp2f(a[j] + madd);
        sP[wave][l4*4+j][n*16+l15] = f2bf_rz(e * rinv[j]);
      }
    }
    // PV MFMA: P from sP (same-wave), V fragments direct from global
    #pragma unroll
    for (int kk=0;kk<2;kk++){
      bf16x8 pf = *(const bf16x8*)(const void*)&sP[wave][l15][kk*32 + l4*8];
      #pragma unroll
      for (int n2=0;n2<4;n2++){
        bf16x8 vf = *(const bf16x8*)(const void*)
            (Vg + (size_t)(n2*16+l15)*NS + kb + kk*32 + l4*8);
        cacc[n2] = __builtin_amdgcn_mfma_f32_16x16x32_bf16(pf, vf, cacc[n2], 0,0,0);
      }
    }
    // dump P tile to attn as nontemporal f32x4; widen via lo<<16 / hi&mask (1 op/elem)
    #pragma unroll
    for (int jj=0;jj<4;jj++){
      const int rr = jj*4 + l4;
      const uint2 pw = *(const uint2*)(const void*)&sP[wave][rr][l15*4];
      f32x4 o;
      o.x = __builtin_bit_cast(float, pw.x << 16);
      o.y = __builtin_bit_cast(float, pw.x & 0xffff0000u);
      o.z = __builtin_bit_cast(float, pw.y << 16);
      o.w = __builtin_bit_cast(float, pw.y & 0xffff0000u);
      __builtin_nontemporal_store(o,
          (f32x4*)(void*)&attn_base[(size_t)(q0 + rr)*NS + kb + l15*4]);
    }
  }
  #pragma unroll
  for (int n2=0;n2<4;n2++)
    #pragma unroll
    for (int j=0;j<4;j++){
      const int q = q0 + l4*4 + j;
      ctx[(((size_t)(b*NS + q)) << 10) + h*HSZ + n2*16 + l15] = f2bf(cacc[n2][j]);
    }
}

// ---------------- in-place LayerNorm over rows of 1024 ----------------
__global__ __launch_bounds__(256) void k_layernorm(float* __restrict__ buf,
    const float* __restrict__ gamma, const float* __restrict__ beta){
  const int row = blockIdx.x, tid = threadIdx.x;
  float4* rp = (float4*)(buf + ((size_t)row << 10));
  float4 a = rp[tid];
  float s  = a.x + a.y + a.z + a.w;
  float ss = a.x*a.x + a.y*a.y + a.z*a.z + a.w*a.w;
  #pragma unroll
  for (int off=1; off<64; off<<=1){
    s  += __shfl_xor(s,  off, 64);
    ss += __shfl_xor(ss, off, 64);
  }
  __shared__ float red[8];
  const int wave = tid>>6, lane = tid&63;
  if (lane == 0){ red[wave] = s; red[wave+4] = ss; }
  __syncthreads();
  s  = red[0]+red[1]+red[2]+red[3];
  ss = red[4]+red[5]+red[6]+red[7];
  const float mu  = s * (1.f/1024.f);
  const float var = ss * (1.f/1024.f) - mu*mu;
  const float rs  = rsqrtf(var + 1e-6f);
  float4 g  = ((const float4*)gamma)[tid];
  float4 be = ((const float4*)beta)[tid];
  float4 o;
  o.x = (a.x-mu)*rs*g.x + be.x;
  o.y = (a.y-mu)*rs*g.y + be.y;
  o.z = (a.z-mu)*rs*g.z + be.z;
  o.w = (a.w-mu)*rs*g.w + be.w;
  rp[tid] = o;
}

extern "C" void kernel_launch(void* const* d_in, const int* in_sizes, int n_in,
                              void* d_out, int out_size, void* d_ws, size_t ws_size,
                              hipStream_t stream){
  const float* x     = (const float*)d_in[0];
  const int*   mask  = (const int*)d_in[1];
  const float* wq_w  = (const float*)d_in[2];
  const float* wq_b  = (const float*)d_in[3];
  const float* wk_w  = (const float*)d_in[4];
  const float* wk_b  = (const float*)d_in[5];
  const float* wv_w  = (const float*)d_in[6];
  const float* wv_b  = (const float*)d_in[7];
  const float* wd_w  = (const float*)d_in[8];
  const float* wd_b  = (const float*)d_in[9];
  const float* gamma = (const float*)d_in[10];
  const float* beta  = (const float*)d_in[11];

  float* out0 = (float*)d_out;                    // [8192][1024] f32
  float* attn = out0 + (size_t)NM * ND;           // [4][16][2048][2048] f32

  char* ws = (char*)d_ws;
  u16*   xb    = (u16*)(ws);                      // 16 MB (aliased by ctx later)
  u16*   ctx   = (u16*)(ws);                      // alias: xb dead after QKV GEMM
  u16*   wcat  = (u16*)(ws + (16u<<20));          // 6 MB: wq^T|wk^T|wv^T
  u16*   wdt   = (u16*)(ws + (22u<<20));          // 2 MB
  u16*   Qb    = (u16*)(ws + (24u<<20));          // 16 MB
  u16*   Kb    = (u16*)(ws + (40u<<20));          // 16 MB
  u16*   Vtb   = (u16*)(ws + (56u<<20));          // 16 MB
  float* stats = (float*)(ws + (72u<<20));        // 0.5 MB -> total 72.5 MB

  k_cast<<<8192, 256, 0, stream>>>((const float4*)x, (ushort4*)xb, NM*ND/4);
  k_transpose4<<<dim3(32,32,4), 256, 0, stream>>>(wq_w, wk_w, wv_w, wd_w, wcat, wdt);

  // fused QKV: C[8192][3072]
  k_gemm<0><<<dim3(64,24), 256, 0, stream>>>(xb, wcat, wq_b, wk_b, wv_b,
                                             nullptr, Qb, Kb, Vtb, nullptr);

  k_attn_stats<<<512, 512, 0, stream>>>(Qb, Kb, mask, stats);
  k_attn_pv<<<1024, 512, 0, stream>>>(Qb, Kb, Vtb, mask, stats, attn, ctx);

  k_gemm<2><<<dim3(64,8), 256, 0, stream>>>(ctx, wdt, wd_b, nullptr, nullptr,
                                            x, nullptr, nullptr, nullptr, out0);
  k_layernorm<<<NM, 256, 0, stream>>>(out0, gamma, beta);
}

// Round 12
// 397.646 us; speedup vs baseline: 1.8446x; 1.8446x over previous
//
#include <hip/hip_runtime.h>
#include <stdint.h>

#define NB 4
#define NS 2048
#define NH 16
#define HSZ 64
#define ND 1024
#define NM (NB*NS)
// exp(x) = exp2(x*log2e); fold 1/sqrt(64)*log2e into Q scale
#define QSCALE 0.180336880f
// mask addend in exp2 domain: -10000*log2e; exp2(a+MADD2) underflows to exact 0
#define MADD2 -14426.950409f

typedef unsigned short u16;
typedef unsigned int u32;
typedef __attribute__((ext_vector_type(4))) float f32x4;
typedef __attribute__((ext_vector_type(8))) __bf16 bf16x8;

static __device__ __forceinline__ u16 f2bf(float f){
  unsigned int x = __builtin_bit_cast(unsigned int, f);
  x += 0x7fffu + ((x >> 16) & 1u);
  return (u16)(x >> 16);
}
// truncating round (P values in [0,1]; <=1ulp error, saves 3 VALU)
static __device__ __forceinline__ u16 f2bf_rz(float f){
  return (u16)(__builtin_bit_cast(unsigned int, f) >> 16);
}

#define GLDS16(gp, lp) __builtin_amdgcn_global_load_lds( \
    (const __attribute__((address_space(1))) void*)(gp),  \
    (__attribute__((address_space(3))) void*)(lp), 16, 0, 0)

// ---------------- cast f32 -> bf16, 4 elems/thread ----------------
__global__ __launch_bounds__(256) void k_cast(const float4* __restrict__ in,
                                              ushort4* __restrict__ out, int n4){
  int i = blockIdx.x*256 + threadIdx.x;
  if (i >= n4) return;
  float4 v = in[i];
  ushort4 o;
  o.x = f2bf(v.x); o.y = f2bf(v.y); o.z = f2bf(v.z); o.w = f2bf(v.w);
  out[i] = o;
}

// --- transpose+cast 1024x1024 x4: wq,wk,wv -> wcat (concat), wd -> wdt ---
__global__ __launch_bounds__(256) void k_transpose4(const float* __restrict__ wq,
    const float* __restrict__ wk, const float* __restrict__ wv,
    const float* __restrict__ wd, u16* __restrict__ wcat, u16* __restrict__ wdt){
  __shared__ float t[32][33];
  const int z = blockIdx.z;
  const float* in = (z==0) ? wq : (z==1) ? wk : (z==2) ? wv : wd;
  u16* out = (z<3) ? (wcat + (size_t)z*ND*ND) : wdt;
  int tx = threadIdx.x & 31, ty = threadIdx.x >> 5;
  int n0 = blockIdx.x*32, k0 = blockIdx.y*32;
  #pragma unroll
  for (int i=0;i<32;i+=8)
    t[ty+i][tx] = in[(size_t)(k0+ty+i)*ND + n0 + tx];
  __syncthreads();
  #pragma unroll
  for (int i=0;i<32;i+=8)
    out[(size_t)(n0+ty+i)*ND + k0 + tx] = f2bf(t[tx][ty+i]);
}

// ---------------- bf16 GEMM core: C[M=8192][N] = A[M][1024] @ Bt[N][1024]^T ----------------
// EPI 0: fused QKV (N=3072): sec 0 -> Q bf16 [B][H][S][64] scaled by QSCALE;
//        sec 1 -> K bf16 same layout; sec 2 -> V^T bf16 [B][H][64][S]
//        (sec 2 output tile transposed through LDS for coalesced 16B stores)
// EPI 2: dense (N=1024): out f32 [M][N] = acc + bias + resid
template<int EPI>
__global__ __launch_bounds__(256,2) void k_gemm(const u16* __restrict__ A,
    const u16* __restrict__ Bt, const float* __restrict__ b0,
    const float* __restrict__ b1, const float* __restrict__ b2,
    const float* __restrict__ resid, u16* __restrict__ Qo, u16* __restrict__ Ko,
    u16* __restrict__ Vto, float* __restrict__ Out){
  __shared__ u16 sAB[2][128*64];
  u16* sA = sAB[0];
  u16* sB = sAB[1];
  const int tid = threadIdx.x;
  const int wave = tid >> 6, lane = tid & 63;
  const int l15 = lane & 15, l4 = lane >> 4;
  const int m0 = blockIdx.x * 128, n0 = blockIdx.y * 128;
  const int wm = wave >> 1, wn = wave & 1;
  const f32x4 vz = {0.f,0.f,0.f,0.f};
  f32x4 acc[4][4];
  #pragma unroll
  for (int i=0;i<4;i++)
    #pragma unroll
    for (int j=0;j<4;j++) acc[i][j] = vz;

  for (int k0 = 0; k0 < 1024; k0 += 64){
    __syncthreads();
    #pragma unroll
    for (int t=0; t<4; t++){
      const int jb = (t*4 + wave)*64;
      const int j  = jb + lane;
      const int r = j >> 3, c = (j & 7) << 3;
      GLDS16(A  + (((size_t)(m0 + r)) << 10) + (size_t)(k0 + c), sA + jb*8);
      GLDS16(Bt + (((size_t)(n0 + r)) << 10) + (size_t)(k0 + c), sB + jb*8);
    }
    __syncthreads();
    #pragma unroll
    for (int kk=0; kk<64; kk+=32){
      bf16x8 af[4], bv[4];
      #pragma unroll
      for (int mi=0;mi<4;mi++)
        af[mi] = *(const bf16x8*)(const void*)(sA + (wm*64 + mi*16 + l15)*64 + kk + l4*8);
      #pragma unroll
      for (int ni=0;ni<4;ni++)
        bv[ni] = *(const bf16x8*)(const void*)(sB + (wn*64 + ni*16 + l15)*64 + kk + l4*8);
      #pragma unroll
      for (int mi=0;mi<4;mi++)
        #pragma unroll
        for (int ni=0;ni<4;ni++)
          acc[mi][ni] = __builtin_amdgcn_mfma_f32_16x16x32_bf16(af[mi], bv[ni], acc[mi][ni], 0, 0, 0);
    }
  }

  if (EPI == 0){
    const int sec = n0 >> 10;                       // block-uniform
    const float* bias = (sec==0) ? b0 : (sec==1) ? b1 : b2;
    const float scale = (sec==0) ? QSCALE : 1.0f;
    if (sec < 2){
      u16* dst = (sec==0) ? Qo : Ko;
      #pragma unroll
      for (int mi=0;mi<4;mi++){
        #pragma unroll
        for (int ni=0;ni<4;ni++){
          const int n = n0 + wn*64 + ni*16 + l15;
          const int nn = n & (ND-1);
          const int h = nn >> 6, d = nn & 63;
          const float bvv = bias[nn];
          #pragma unroll
          for (int j=0;j<4;j++){
            const int m = m0 + wm*64 + mi*16 + l4*4 + j;
            const int b = m >> 11, s = m & (NS-1);
            const float v = (acc[mi][ni][j] + bvv) * scale;
            dst[((((size_t)b*NH + h)*NS + s) << 6) + d] = f2bf(v);
          }
        }
      }
    } else {
      // V^T: transpose tile through LDS (sAB dead after K-loop), coalesced stores
      __syncthreads();
      u16 (*sT)[128] = (u16(*)[128])sAB;
      #pragma unroll
      for (int mi=0;mi<4;mi++){
        #pragma unroll
        for (int ni=0;ni<4;ni++){
          const int nl = wn*64 + ni*16 + l15;      // local n (d-direction)
          const float bvv = bias[(n0 & (ND-1)) + nl];
          #pragma unroll
          for (int j=0;j<4;j++){
            const int ml = wm*64 + mi*16 + l4*4 + j;  // local m (s-direction)
            sT[nl][ml] = f2bf(acc[mi][ni][j] + bvv);
          }
        }
      }
      __syncthreads();
      const int nbase = n0 & (ND-1);
      const int b2 = m0 >> 11;
      const int sbase = m0 & (NS-1);
      #pragma unroll
      for (int it=0; it<8; ++it){
        const int idx = it*256 + tid;
        const int row = idx >> 4;                 // 0..127 local d
        const int ch  = (idx & 15) << 3;          // 0..120 local s (u16 units)
        const int nn2 = nbase + row;
        const int h2 = nn2 >> 6, d2 = nn2 & 63;
        *(int4*)(void*)(Vto + ((((size_t)b2*NH + h2)*HSZ + d2) << 11) + sbase + ch)
            = *(const int4*)(const void*)&sT[row][ch];
      }
    }
  } else {
    #pragma unroll
    for (int mi=0;mi<4;mi++){
      #pragma unroll
      for (int ni=0;ni<4;ni++){
        const int n = n0 + wn*64 + ni*16 + l15;
        const float bvv = b0[n];
        #pragma unroll
        for (int j=0;j<4;j++){
          const int m = m0 + wm*64 + mi*16 + l4*4 + j;
          const size_t o = ((size_t)m << 10) + n;
          Out[o] = acc[mi][ni][j] + bvv + resid[o];
        }
      }
    }
  }
}

// XCD-aware decode, pv grid (1024 blocks): bid = x + 8*(qb + 16*ghi)
static __device__ __forceinline__ void attn_decode(int bid, int& qb, int& bh){
  const int x = bid & 7, t = bid >> 3;
  qb = t & 15;
  bh = (t >> 4) * 8 + x;
}
// XCD-aware decode, stats grid (512 blocks, qb in 0..7): bid = x + 8*(qb + 8*ghi)
static __device__ __forceinline__ void attn_decode8(int bid, int& qb, int& bh){
  const int x = bid & 7, t = bid >> 3;
  qb = t & 7;
  bh = (t >> 3) * 8 + x;
}

// ------- attention pass 1: per-row 1/sum(exp2(s')) (fixed max = 0) -------
// 512 threads, 8 waves, 256 q-rows per block (wave owns 32 rows = 2 subtiles);
// K-fragments from LDS reused across both row-subtiles.
// 2-deep pipelined K staging, single barrier per k-tile; grid 512 = 2 blocks/CU.
__global__ __launch_bounds__(512,4) void k_attn_stats(const u16* __restrict__ Q,
    const u16* __restrict__ K, const int* __restrict__ mask,
    float* __restrict__ stats){
  __shared__ u16 sK[2][64][72];
  __shared__ float sMadd[NS];
  const int tid = threadIdx.x, wave = tid>>6, lane = tid&63;
  const int l15 = lane&15, l4 = lane>>4;
  int qb, bh; attn_decode8(blockIdx.x, qb, bh);
  const int b = bh >> 4;
  const size_t hoff = (size_t)bh * NS * HSZ;
  const int q0 = qb*256 + wave*32;
  const u16* Kg = K + hoff;
  bf16x8 qf0[2], qf1[2];
  #pragma unroll
  for (int m=0;m<2;m++){
    qf0[m] = *(const bf16x8*)(const void*)(Q + hoff + (size_t)(q0+m*16+l15)*HSZ + l4*8);
    qf1[m] = *(const bf16x8*)(const void*)(Q + hoff + (size_t)(q0+m*16+l15)*HSZ + 32 + l4*8);
  }
  const f32x4 vz = {0.f,0.f,0.f,0.f};
  const int r = tid >> 3, c = (tid & 7) << 3;     // 512 threads cover 64x64
  float lr[2][4] = {{0.f,0.f,0.f,0.f},{0.f,0.f,0.f,0.f}};

  #pragma unroll
  for (int t=0;t<4;t++){
    const int kk = t*512 + tid;
    sMadd[kk] = mask[b*NS + kk] ? MADD2 : 0.f;
  }
  // prologue: tile 0 -> buf0; tile 1 -> regs
  int4 rK = *(const int4*)(const void*)(Kg + (size_t)r*HSZ + c);
  *(int4*)(void*)&sK[0][r][c] = rK;
  rK = *(const int4*)(const void*)(Kg + (size_t)(64+r)*HSZ + c);
  __syncthreads();

  for (int kb=0; kb<NS; kb+=64){
    const int cur = (kb>>6)&1;
    if (kb+64 < NS)
      *(int4*)(void*)&sK[cur^1][r][c] = rK;
    if (kb+128 < NS)
      rK = *(const int4*)(const void*)(Kg + (size_t)(kb+128+r)*HSZ + c);
    #pragma unroll
    for (int n=0;n<4;n++){
      bf16x8 kf0 = *(const bf16x8*)(const void*)&sK[cur][n*16+l15][l4*8];
      bf16x8 kf1 = *(const bf16x8*)(const void*)&sK[cur][n*16+l15][32+l4*8];
      const float madd = sMadd[kb + n*16 + l15];
      #pragma unroll
      for (int m=0;m<2;m++){
        f32x4 a = vz;
        a = __builtin_amdgcn_mfma_f32_16x16x32_bf16(qf0[m], kf0, a, 0,0,0);
        a = __builtin_amdgcn_mfma_f32_16x16x32_bf16(qf1[m], kf1, a, 0,0,0);
        #pragma unroll
        for (int j=0;j<4;j++)
          lr[m][j] += __builtin_amdgcn_exp2f(a[j] + madd);
      }
    }
    __syncthreads();
  }
  #pragma unroll
  for (int m=0;m<2;m++)
    #pragma unroll
    for (int j=0;j<4;j++){
      float l = lr[m][j];
      #pragma unroll
      for (int off=1; off<16; off<<=1)
        l += __shfl_xor(l, off, 64);
      if (l15 == 0)
        stats[(size_t)bh*NS + q0 + m*16 + l4*4 + j] = 1.f/l;
    }
}

// --------- attention pass 2: recompute scores, write attn f32, ctx = P@V ---------
// 512 threads, 8 waves, 128 q-rows per block; 2-deep pipelined K/V staging,
// single barrier per k-tile; mask staged in LDS
__global__ __launch_bounds__(512,4) void k_attn_pv(const u16* __restrict__ Q,
    const u16* __restrict__ K, const u16* __restrict__ Vt,
    const int* __restrict__ mask, const float* __restrict__ stats,
    float* __restrict__ attn, u16* __restrict__ ctx){
  __shared__ u16 sK[2][64][72];
  __shared__ u16 sV[2][64][72];
  __shared__ u16 sP[8][16][72];
  __shared__ float sMadd[NS];
  const int tid = threadIdx.x, wave = tid>>6, lane = tid&63;
  const int l15 = lane&15, l4 = lane>>4;
  int qb, bh; attn_decode(blockIdx.x, qb, bh);
  const int b = bh >> 4, h = bh & 15;
  const size_t hoff = (size_t)bh * NS * HSZ;
  const int q0 = qb*128 + wave*16;
  const u16* Kg = K + hoff;
  const u16* Vg = Vt + hoff;
  const bf16x8 qf0 = *(const bf16x8*)(const void*)(Q + hoff + (size_t)(q0+l15)*HSZ + l4*8);
  const bf16x8 qf1 = *(const bf16x8*)(const void*)(Q + hoff + (size_t)(q0+l15)*HSZ + 32 + l4*8);
  float rinv[4];
  #pragma unroll
  for (int j=0;j<4;j++)
    rinv[j] = stats[(size_t)bh*NS + q0 + l4*4 + j];
  const f32x4 vz = {0.f,0.f,0.f,0.f};
  f32x4 cacc[4];
  #pragma unroll
  for (int i=0;i<4;i++) cacc[i] = vz;
  float* attn_base = attn + (size_t)bh * NS * NS;
  const int r = tid >> 3, c = (tid & 7) << 3;     // 512 threads cover 64x64

  #pragma unroll
  for (int t=0;t<4;t++){
    const int kk = t*512 + tid;
    sMadd[kk] = mask[b*NS + kk] ? MADD2 : 0.f;
  }
  // prologue: tile 0 -> buf0; tile 1 -> regs
  int4 rK = *(const int4*)(const void*)(Kg + (size_t)r*HSZ + c);
  int4 rV = *(const int4*)(const void*)(Vg + (size_t)r*NS + c);
  *(int4*)(void*)&sK[0][r][c] = rK;
  *(int4*)(void*)&sV[0][r][c] = rV;
  rK = *(const int4*)(const void*)(Kg + (size_t)(64+r)*HSZ + c);
  rV = *(const int4*)(const void*)(Vg + (size_t)r*NS + 64 + c);
  __syncthreads();

  for (int kb=0; kb<NS; kb+=64){
    const int cur = (kb>>6)&1;
    if (kb+64 < NS){
      *(int4*)(void*)&sK[cur^1][r][c] = rK;
      *(int4*)(void*)&sV[cur^1][r][c] = rV;
    }
    if (kb+128 < NS){
      rK = *(const int4*)(const void*)(Kg + (size_t)(kb+128+r)*HSZ + c);
      rV = *(const int4*)(const void*)(Vg + (size_t)r*NS + (kb+128) + c);
    }
    #pragma unroll
    for (int n=0;n<4;n++){
      bf16x8 kf0 = *(const bf16x8*)(const void*)&sK[cur][n*16+l15][l4*8];
      bf16x8 kf1 = *(const bf16x8*)(const void*)&sK[cur][n*16+l15][32+l4*8];
      f32x4 a = vz;
      a = __builtin_amdgcn_mfma_f32_16x16x32_bf16(qf0, kf0, a, 0,0,0);
      a = __builtin_amdgcn_mfma_f32_16x16x32_bf16(qf1, kf1, a, 0,0,0);
      const float madd = sMadd[kb + n*16 + l15];
      #pragma unroll
      for (int j=0;j<4;j++){
        const float e = __builtin_amdgcn_exp2f(a[j] + madd);
        sP[wave][l4*4+j][n*16+l15] = f2bf_rz(e * rinv[j]);
      }
    }
    // PV MFMA from sP (same-wave produce/consume)
    #pragma unroll
    for (int kk=0;kk<2;kk++){
      bf16x8 pf = *(const bf16x8*)(const void*)&sP[wave][l15][kk*32 + l4*8];
      #pragma unroll
      for (int n2=0;n2<4;n2++){
        bf16x8 vf = *(const bf16x8*)(const void*)&sV[cur][n2*16+l15][kk*32 + l4*8];
        cacc[n2] = __builtin_amdgcn_mfma_f32_16x16x32_bf16(pf, vf, cacc[n2], 0,0,0);
      }
    }
    // dump P tile to attn as nontemporal f32x4; widen via lo<<16 / hi&mask (1 op/elem)
    #pragma unroll
    for (int jj=0;jj<4;jj++){
      const int rr = jj*4 + l4;
      const uint2 pw = *(const uint2*)(const void*)&sP[wave][rr][l15*4];
      f32x4 o;
      o.x = __builtin_bit_cast(float, pw.x << 16);
      o.y = __builtin_bit_cast(float, pw.x & 0xffff0000u);
      o.z = __builtin_bit_cast(float, pw.y << 16);
      o.w = __builtin_bit_cast(float, pw.y & 0xffff0000u);
      __builtin_nontemporal_store(o,
          (f32x4*)(void*)&attn_base[(size_t)(q0 + rr)*NS + kb + l15*4]);
    }
    __syncthreads();
  }
  #pragma unroll
  for (int n2=0;n2<4;n2++)
    #pragma unroll
    for (int j=0;j<4;j++){
      const int q = q0 + l4*4 + j;
      ctx[(((size_t)(b*NS + q)) << 10) + h*HSZ + n2*16 + l15] = f2bf(cacc[n2][j]);
    }
}

// ---------------- in-place LayerNorm over rows of 1024 ----------------
__global__ __launch_bounds__(256) void k_layernorm(float* __restrict__ buf,
    const float* __restrict__ gamma, const float* __restrict__ beta){
  const int row = blockIdx.x, tid = threadIdx.x;
  float4* rp = (float4*)(buf + ((size_t)row << 10));
  float4 a = rp[tid];
  float s  = a.x + a.y + a.z + a.w;
  float ss = a.x*a.x + a.y*a.y + a.z*a.z + a.w*a.w;
  #pragma unroll
  for (int off=1; off<64; off<<=1){
    s  += __shfl_xor(s,  off, 64);
    ss += __shfl_xor(ss, off, 64);
  }
  __shared__ float red[8];
  const int wave = tid>>6, lane = tid&63;
  if (lane == 0){ red[wave] = s; red[wave+4] = ss; }
  __syncthreads();
  s  = red[0]+red[1]+red[2]+red[3];
  ss = red[4]+red[5]+red[6]+red[7];
  const float mu  = s * (1.f/1024.f);
  const float var = ss * (1.f/1024.f) - mu*mu;
  const float rs  = rsqrtf(var + 1e-6f);
  float4 g  = ((const float4*)gamma)[tid];
  float4 be = ((const float4*)beta)[tid];
  f32x4 o;
  o.x = (a.x-mu)*rs*g.x + be.x;
  o.y = (a.y-mu)*rs*g.y + be.y;
  o.z = (a.z-mu)*rs*g.z + be.z;
  o.w = (a.w-mu)*rs*g.w + be.w;
  __builtin_nontemporal_store(o, (f32x4*)(void*)&rp[tid]);
}

extern "C" void kernel_launch(void* const* d_in, const int* in_sizes, int n_in,
                              void* d_out, int out_size, void* d_ws, size_t ws_size,
                              hipStream_t stream){
  const float* x     = (const float*)d_in[0];
  const int*   mask  = (const int*)d_in[1];
  const float* wq_w  = (const float*)d_in[2];
  const float* wq_b  = (const float*)d_in[3];
  const float* wk_w  = (const float*)d_in[4];
  const float* wk_b  = (const float*)d_in[5];
  const float* wv_w  = (const float*)d_in[6];
  const float* wv_b  = (const float*)d_in[7];
  const float* wd_w  = (const float*)d_in[8];
  const float* wd_b  = (const float*)d_in[9];
  const float* gamma = (const float*)d_in[10];
  const float* beta  = (const float*)d_in[11];

  float* out0 = (float*)d_out;                    // [8192][1024] f32
  float* attn = out0 + (size_t)NM * ND;           // [4][16][2048][2048] f32

  char* ws = (char*)d_ws;
  u16*   xb    = (u16*)(ws);                      // 16 MB (aliased by ctx later)
  u16*   ctx   = (u16*)(ws);                      // alias: xb dead after QKV GEMM
  u16*   wcat  = (u16*)(ws + (16u<<20));          // 6 MB: wq^T|wk^T|wv^T
  u16*   wdt   = (u16*)(ws + (22u<<20));          // 2 MB
  u16*   Qb    = (u16*)(ws + (24u<<20));          // 16 MB
  u16*   Kb    = (u16*)(ws + (40u<<20));          // 16 MB
  u16*   Vtb   = (u16*)(ws + (56u<<20));          // 16 MB
  float* stats = (float*)(ws + (72u<<20));        // 0.5 MB -> total 72.5 MB

  k_cast<<<8192, 256, 0, stream>>>((const float4*)x, (ushort4*)xb, NM*ND/4);
  k_transpose4<<<dim3(32,32,4), 256, 0, stream>>>(wq_w, wk_w, wv_w, wd_w, wcat, wdt);

  // fused QKV: C[8192][3072]
  k_gemm<0><<<dim3(64,24), 256, 0, stream>>>(xb, wcat, wq_b, wk_b, wv_b,
                                             nullptr, Qb, Kb, Vtb, nullptr);

  k_attn_stats<<<512, 512, 0, stream>>>(Qb, Kb, mask, stats);
  k_attn_pv<<<1024, 512, 0, stream>>>(Qb, Kb, Vtb, mask, stats, attn, ctx);

  k_gemm<2><<<dim3(64,8), 256, 0, stream>>>(ctx, wdt, wd_b, nullptr, nullptr,
                                            x, nullptr, nullptr, nullptr, out0);
  k_layernorm<<<NM, 256, 0, stream>>>(out0, gamma, beta);
}

// Round 13
// 365.894 us; speedup vs baseline: 2.0046x; 1.0868x over previous
//
#include <hip/hip_runtime.h>
#include <stdint.h>

#define NB 4
#define NS 2048
#define NH 16
#define HSZ 64
#define ND 1024
#define NM (NB*NS)
// exp(x) = exp2(x*log2e); fold 1/sqrt(64)*log2e into Q scale
#define QSCALE 0.180336880f
// mask addend in exp2 domain: -10000*log2e; exp2(a+MADD2) underflows to exact 0
#define MADD2 -14426.950409f

typedef unsigned short u16;
typedef unsigned int u32;
typedef __attribute__((ext_vector_type(4))) float f32x4;
typedef __attribute__((ext_vector_type(8))) __bf16 bf16x8;

static __device__ __forceinline__ u16 f2bf(float f){
  unsigned int x = __builtin_bit_cast(unsigned int, f);
  x += 0x7fffu + ((x >> 16) & 1u);
  return (u16)(x >> 16);
}
// truncating round (P values in [0,1]; <=1ulp error, saves 3 VALU)
static __device__ __forceinline__ u16 f2bf_rz(float f){
  return (u16)(__builtin_bit_cast(unsigned int, f) >> 16);
}

#define GLDS16(gp, lp) __builtin_amdgcn_global_load_lds( \
    (const __attribute__((address_space(1))) void*)(gp),  \
    (__attribute__((address_space(3))) void*)(lp), 16, 0, 0)

// ---------------- cast f32 -> bf16, 4 elems/thread ----------------
__global__ __launch_bounds__(256) void k_cast(const float4* __restrict__ in,
                                              ushort4* __restrict__ out, int n4){
  int i = blockIdx.x*256 + threadIdx.x;
  if (i >= n4) return;
  float4 v = in[i];
  ushort4 o;
  o.x = f2bf(v.x); o.y = f2bf(v.y); o.z = f2bf(v.z); o.w = f2bf(v.w);
  out[i] = o;
}

// --- transpose+cast 1024x1024 x4: wq,wk,wv -> wcat (concat), wd -> wdt ---
__global__ __launch_bounds__(256) void k_transpose4(const float* __restrict__ wq,
    const float* __restrict__ wk, const float* __restrict__ wv,
    const float* __restrict__ wd, u16* __restrict__ wcat, u16* __restrict__ wdt){
  __shared__ float t[32][33];
  const int z = blockIdx.z;
  const float* in = (z==0) ? wq : (z==1) ? wk : (z==2) ? wv : wd;
  u16* out = (z<3) ? (wcat + (size_t)z*ND*ND) : wdt;
  int tx = threadIdx.x & 31, ty = threadIdx.x >> 5;
  int n0 = blockIdx.x*32, k0 = blockIdx.y*32;
  #pragma unroll
  for (int i=0;i<32;i+=8)
    t[ty+i][tx] = in[(size_t)(k0+ty+i)*ND + n0 + tx];
  __syncthreads();
  #pragma unroll
  for (int i=0;i<32;i+=8)
    out[(size_t)(n0+ty+i)*ND + k0 + tx] = f2bf(t[tx][ty+i]);
}

// ---------------- bf16 GEMM core: C[M=8192][N] = A[M][1024] @ Bt[N][1024]^T ----------------
// EPI 0: fused QKV (N=3072): sec 0 -> Q bf16 [B][H][S][64] scaled by QSCALE;
//        sec 1 -> K bf16 same layout; sec 2 -> V^T bf16 [B][H][64][S]
//        (sec 2 output tile transposed through LDS for coalesced 16B stores)
// EPI 2: dense (N=1024): out f32 [M][N] = acc + bias + resid
template<int EPI>
__global__ __launch_bounds__(256,2) void k_gemm(const u16* __restrict__ A,
    const u16* __restrict__ Bt, const float* __restrict__ b0,
    const float* __restrict__ b1, const float* __restrict__ b2,
    const float* __restrict__ resid, u16* __restrict__ Qo, u16* __restrict__ Ko,
    u16* __restrict__ Vto, float* __restrict__ Out){
  __shared__ u16 sAB[2][128*64];
  u16* sA = sAB[0];
  u16* sB = sAB[1];
  const int tid = threadIdx.x;
  const int wave = tid >> 6, lane = tid & 63;
  const int l15 = lane & 15, l4 = lane >> 4;
  const int m0 = blockIdx.x * 128, n0 = blockIdx.y * 128;
  const int wm = wave >> 1, wn = wave & 1;
  const f32x4 vz = {0.f,0.f,0.f,0.f};
  f32x4 acc[4][4];
  #pragma unroll
  for (int i=0;i<4;i++)
    #pragma unroll
    for (int j=0;j<4;j++) acc[i][j] = vz;

  for (int k0 = 0; k0 < 1024; k0 += 64){
    __syncthreads();
    #pragma unroll
    for (int t=0; t<4; t++){
      const int jb = (t*4 + wave)*64;
      const int j  = jb + lane;
      const int r = j >> 3, c = (j & 7) << 3;
      GLDS16(A  + (((size_t)(m0 + r)) << 10) + (size_t)(k0 + c), sA + jb*8);
      GLDS16(Bt + (((size_t)(n0 + r)) << 10) + (size_t)(k0 + c), sB + jb*8);
    }
    __syncthreads();
    #pragma unroll
    for (int kk=0; kk<64; kk+=32){
      bf16x8 af[4], bv[4];
      #pragma unroll
      for (int mi=0;mi<4;mi++)
        af[mi] = *(const bf16x8*)(const void*)(sA + (wm*64 + mi*16 + l15)*64 + kk + l4*8);
      #pragma unroll
      for (int ni=0;ni<4;ni++)
        bv[ni] = *(const bf16x8*)(const void*)(sB + (wn*64 + ni*16 + l15)*64 + kk + l4*8);
      #pragma unroll
      for (int mi=0;mi<4;mi++)
        #pragma unroll
        for (int ni=0;ni<4;ni++)
          acc[mi][ni] = __builtin_amdgcn_mfma_f32_16x16x32_bf16(af[mi], bv[ni], acc[mi][ni], 0, 0, 0);
    }
  }

  if (EPI == 0){
    const int sec = n0 >> 10;                       // block-uniform
    const float* bias = (sec==0) ? b0 : (sec==1) ? b1 : b2;
    const float scale = (sec==0) ? QSCALE : 1.0f;
    if (sec < 2){
      u16* dst = (sec==0) ? Qo : Ko;
      #pragma unroll
      for (int mi=0;mi<4;mi++){
        #pragma unroll
        for (int ni=0;ni<4;ni++){
          const int n = n0 + wn*64 + ni*16 + l15;
          const int nn = n & (ND-1);
          const int h = nn >> 6, d = nn & 63;
          const float bvv = bias[nn];
          #pragma unroll
          for (int j=0;j<4;j++){
            const int m = m0 + wm*64 + mi*16 + l4*4 + j;
            const int b = m >> 11, s = m & (NS-1);
            const float v = (acc[mi][ni][j] + bvv) * scale;
            dst[((((size_t)b*NH + h)*NS + s) << 6) + d] = f2bf(v);
          }
        }
      }
    } else {
      // V^T: transpose tile through LDS (sAB dead after K-loop), coalesced stores
      __syncthreads();
      u16 (*sT)[128] = (u16(*)[128])sAB;
      #pragma unroll
      for (int mi=0;mi<4;mi++){
        #pragma unroll
        for (int ni=0;ni<4;ni++){
          const int nl = wn*64 + ni*16 + l15;      // local n (d-direction)
          const float bvv = bias[(n0 & (ND-1)) + nl];
          #pragma unroll
          for (int j=0;j<4;j++){
            const int ml = wm*64 + mi*16 + l4*4 + j;  // local m (s-direction)
            sT[nl][ml] = f2bf(acc[mi][ni][j] + bvv);
          }
        }
      }
      __syncthreads();
      const int nbase = n0 & (ND-1);
      const int b2 = m0 >> 11;
      const int sbase = m0 & (NS-1);
      #pragma unroll
      for (int it=0; it<8; ++it){
        const int idx = it*256 + tid;
        const int row = idx >> 4;                 // 0..127 local d
        const int ch  = (idx & 15) << 3;          // 0..120 local s (u16 units)
        const int nn2 = nbase + row;
        const int h2 = nn2 >> 6, d2 = nn2 & 63;
        *(int4*)(void*)(Vto + ((((size_t)b2*NH + h2)*HSZ + d2) << 11) + sbase + ch)
            = *(const int4*)(const void*)&sT[row][ch];
      }
    }
  } else {
    #pragma unroll
    for (int mi=0;mi<4;mi++){
      #pragma unroll
      for (int ni=0;ni<4;ni++){
        const int n = n0 + wn*64 + ni*16 + l15;
        const float bvv = b0[n];
        #pragma unroll
        for (int j=0;j<4;j++){
          const int m = m0 + wm*64 + mi*16 + l4*4 + j;
          const size_t o = ((size_t)m << 10) + n;
          Out[o] = acc[mi][ni][j] + bvv + resid[o];
        }
      }
    }
  }
}

// XCD-aware decode, attn grid (1024 blocks): bid = x + 8*(qb + 16*ghi)
static __device__ __forceinline__ void attn_decode(int bid, int& qb, int& bh){
  const int x = bid & 7, t = bid >> 3;
  qb = t & 15;
  bh = (t >> 4) * 8 + x;
}

// ---- fused attention: phase A row-sums (K-only), phase B attn write + P@V ----
// 512 threads, 8 waves, 128 q-rows per block; both phases 2-deep pipelined,
// single barrier per k-tile; mask staged in LDS; rinv stays in registers.
__global__ __launch_bounds__(512,4) void k_attn_fused(const u16* __restrict__ Q,
    const u16* __restrict__ K, const u16* __restrict__ Vt,
    const int* __restrict__ mask, float* __restrict__ attn, u16* __restrict__ ctx){
  __shared__ u16 sK[2][64][72];
  __shared__ u16 sV[2][64][72];
  __shared__ u16 sP[8][16][72];
  __shared__ float sMadd[NS];
  const int tid = threadIdx.x, wave = tid>>6, lane = tid&63;
  const int l15 = lane&15, l4 = lane>>4;
  int qb, bh; attn_decode(blockIdx.x, qb, bh);
  const int b = bh >> 4, h = bh & 15;
  const size_t hoff = (size_t)bh * NS * HSZ;
  const int q0 = qb*128 + wave*16;
  const u16* Kg = K + hoff;
  const u16* Vg = Vt + hoff;
  const bf16x8 qf0 = *(const bf16x8*)(const void*)(Q + hoff + (size_t)(q0+l15)*HSZ + l4*8);
  const bf16x8 qf1 = *(const bf16x8*)(const void*)(Q + hoff + (size_t)(q0+l15)*HSZ + 32 + l4*8);
  const f32x4 vz = {0.f,0.f,0.f,0.f};
  const int r = tid >> 3, c = (tid & 7) << 3;     // 512 threads cover 64x64

  #pragma unroll
  for (int t=0;t<4;t++){
    const int kk = t*512 + tid;
    sMadd[kk] = mask[b*NS + kk] ? MADD2 : 0.f;
  }

  // ---------------- phase A: row sums of exp2 (K-only pipeline) ----------------
  float lr[4] = {0.f,0.f,0.f,0.f};
  {
    int4 rK = *(const int4*)(const void*)(Kg + (size_t)r*HSZ + c);
    *(int4*)(void*)&sK[0][r][c] = rK;
    rK = *(const int4*)(const void*)(Kg + (size_t)(64+r)*HSZ + c);
    __syncthreads();
    for (int kb=0; kb<NS; kb+=64){
      const int cur = (kb>>6)&1;
      if (kb+64 < NS)
        *(int4*)(void*)&sK[cur^1][r][c] = rK;
      if (kb+128 < NS)
        rK = *(const int4*)(const void*)(Kg + (size_t)(kb+128+r)*HSZ + c);
      #pragma unroll
      for (int n=0;n<4;n++){
        bf16x8 kf0 = *(const bf16x8*)(const void*)&sK[cur][n*16+l15][l4*8];
        bf16x8 kf1 = *(const bf16x8*)(const void*)&sK[cur][n*16+l15][32+l4*8];
        f32x4 a = vz;
        a = __builtin_amdgcn_mfma_f32_16x16x32_bf16(qf0, kf0, a, 0,0,0);
        a = __builtin_amdgcn_mfma_f32_16x16x32_bf16(qf1, kf1, a, 0,0,0);
        const float madd = sMadd[kb + n*16 + l15];
        #pragma unroll
        for (int j=0;j<4;j++)
          lr[j] += __builtin_amdgcn_exp2f(a[j] + madd);
      }
      __syncthreads();
    }
  }
  float rinv[4];
  #pragma unroll
  for (int j=0;j<4;j++){
    float l = lr[j];
    #pragma unroll
    for (int off=1; off<16; off<<=1)
      l += __shfl_xor(l, off, 64);
    rinv[j] = 1.f/l;                 // all lanes of the 16-group hold the sum
  }

  // ---------------- phase B: attn write + P@V (K+V pipeline) ----------------
  f32x4 cacc[4];
  #pragma unroll
  for (int i=0;i<4;i++) cacc[i] = vz;
  float* attn_base = attn + (size_t)bh * NS * NS;

  // prologue (phase A's final barrier already passed; LDS free)
  int4 rK = *(const int4*)(const void*)(Kg + (size_t)r*HSZ + c);
  int4 rV = *(const int4*)(const void*)(Vg + (size_t)r*NS + c);
  *(int4*)(void*)&sK[0][r][c] = rK;
  *(int4*)(void*)&sV[0][r][c] = rV;
  rK = *(const int4*)(const void*)(Kg + (size_t)(64+r)*HSZ + c);
  rV = *(const int4*)(const void*)(Vg + (size_t)r*NS + 64 + c);
  __syncthreads();

  for (int kb=0; kb<NS; kb+=64){
    const int cur = (kb>>6)&1;
    if (kb+64 < NS){
      *(int4*)(void*)&sK[cur^1][r][c] = rK;
      *(int4*)(void*)&sV[cur^1][r][c] = rV;
    }
    if (kb+128 < NS){
      rK = *(const int4*)(const void*)(Kg + (size_t)(kb+128+r)*HSZ + c);
      rV = *(const int4*)(const void*)(Vg + (size_t)r*NS + (kb+128) + c);
    }
    #pragma unroll
    for (int n=0;n<4;n++){
      bf16x8 kf0 = *(const bf16x8*)(const void*)&sK[cur][n*16+l15][l4*8];
      bf16x8 kf1 = *(const bf16x8*)(const void*)&sK[cur][n*16+l15][32+l4*8];
      f32x4 a = vz;
      a = __builtin_amdgcn_mfma_f32_16x16x32_bf16(qf0, kf0, a, 0,0,0);
      a = __builtin_amdgcn_mfma_f32_16x16x32_bf16(qf1, kf1, a, 0,0,0);
      const float madd = sMadd[kb + n*16 + l15];
      #pragma unroll
      for (int j=0;j<4;j++){
        const float e = __builtin_amdgcn_exp2f(a[j] + madd);
        sP[wave][l4*4+j][n*16+l15] = f2bf_rz(e * rinv[j]);
      }
    }
    // PV MFMA from sP (same-wave produce/consume)
    #pragma unroll
    for (int kk=0;kk<2;kk++){
      bf16x8 pf = *(const bf16x8*)(const void*)&sP[wave][l15][kk*32 + l4*8];
      #pragma unroll
      for (int n2=0;n2<4;n2++){
        bf16x8 vf = *(const bf16x8*)(const void*)&sV[cur][n2*16+l15][kk*32 + l4*8];
        cacc[n2] = __builtin_amdgcn_mfma_f32_16x16x32_bf16(pf, vf, cacc[n2], 0,0,0);
      }
    }
    // dump P tile to attn as nontemporal f32x4; widen via lo<<16 / hi&mask (1 op/elem)
    #pragma unroll
    for (int jj=0;jj<4;jj++){
      const int rr = jj*4 + l4;
      const uint2 pw = *(const uint2*)(const void*)&sP[wave][rr][l15*4];
      f32x4 o;
      o.x = __builtin_bit_cast(float, pw.x << 16);
      o.y = __builtin_bit_cast(float, pw.x & 0xffff0000u);
      o.z = __builtin_bit_cast(float, pw.y << 16);
      o.w = __builtin_bit_cast(float, pw.y & 0xffff0000u);
      __builtin_nontemporal_store(o,
          (f32x4*)(void*)&attn_base[(size_t)(q0 + rr)*NS + kb + l15*4]);
    }
    __syncthreads();
  }
  #pragma unroll
  for (int n2=0;n2<4;n2++)
    #pragma unroll
    for (int j=0;j<4;j++){
      const int q = q0 + l4*4 + j;
      ctx[(((size_t)(b*NS + q)) << 10) + h*HSZ + n2*16 + l15] = f2bf(cacc[n2][j]);
    }
}

// ---------------- in-place LayerNorm over rows of 1024 ----------------
__global__ __launch_bounds__(256) void k_layernorm(float* __restrict__ buf,
    const float* __restrict__ gamma, const float* __restrict__ beta){
  const int row = blockIdx.x, tid = threadIdx.x;
  float4* rp = (float4*)(buf + ((size_t)row << 10));
  float4 a = rp[tid];
  float s  = a.x + a.y + a.z + a.w;
  float ss = a.x*a.x + a.y*a.y + a.z*a.z + a.w*a.w;
  #pragma unroll
  for (int off=1; off<64; off<<=1){
    s  += __shfl_xor(s,  off, 64);
    ss += __shfl_xor(ss, off, 64);
  }
  __shared__ float red[8];
  const int wave = tid>>6, lane = tid&63;
  if (lane == 0){ red[wave] = s; red[wave+4] = ss; }
  __syncthreads();
  s  = red[0]+red[1]+red[2]+red[3];
  ss = red[4]+red[5]+red[6]+red[7];
  const float mu  = s * (1.f/1024.f);
  const float var = ss * (1.f/1024.f) - mu*mu;
  const float rs  = rsqrtf(var + 1e-6f);
  float4 g  = ((const float4*)gamma)[tid];
  float4 be = ((const float4*)beta)[tid];
  f32x4 o;
  o.x = (a.x-mu)*rs*g.x + be.x;
  o.y = (a.y-mu)*rs*g.y + be.y;
  o.z = (a.z-mu)*rs*g.z + be.z;
  o.w = (a.w-mu)*rs*g.w + be.w;
  __builtin_nontemporal_store(o, (f32x4*)(void*)&rp[tid]);
}

extern "C" void kernel_launch(void* const* d_in, const int* in_sizes, int n_in,
                              void* d_out, int out_size, void* d_ws, size_t ws_size,
                              hipStream_t stream){
  const float* x     = (const float*)d_in[0];
  const int*   mask  = (const int*)d_in[1];
  const float* wq_w  = (const float*)d_in[2];
  const float* wq_b  = (const float*)d_in[3];
  const float* wk_w  = (const float*)d_in[4];
  const float* wk_b  = (const float*)d_in[5];
  const float* wv_w  = (const float*)d_in[6];
  const float* wv_b  = (const float*)d_in[7];
  const float* wd_w  = (const float*)d_in[8];
  const float* wd_b  = (const float*)d_in[9];
  const float* gamma = (const float*)d_in[10];
  const float* beta  = (const float*)d_in[11];

  float* out0 = (float*)d_out;                    // [8192][1024] f32
  float* attn = out0 + (size_t)NM * ND;           // [4][16][2048][2048] f32

  char* ws = (char*)d_ws;
  u16*   xb    = (u16*)(ws);                      // 16 MB (aliased by ctx later)
  u16*   ctx   = (u16*)(ws);                      // alias: xb dead after QKV GEMM
  u16*   wcat  = (u16*)(ws + (16u<<20));          // 6 MB: wq^T|wk^T|wv^T
  u16*   wdt   = (u16*)(ws + (22u<<20));          // 2 MB
  u16*   Qb    = (u16*)(ws + (24u<<20));          // 16 MB
  u16*   Kb    = (u16*)(ws + (40u<<20));          // 16 MB
  u16*   Vtb   = (u16*)(ws + (56u<<20));          // 16 MB -> 72 MB total

  k_cast<<<8192, 256, 0, stream>>>((const float4*)x, (ushort4*)xb, NM*ND/4);
  k_transpose4<<<dim3(32,32,4), 256, 0, stream>>>(wq_w, wk_w, wv_w, wd_w, wcat, wdt);

  // fused QKV: C[8192][3072]
  k_gemm<0><<<dim3(64,24), 256, 0, stream>>>(xb, wcat, wq_b, wk_b, wv_b,
                                             nullptr, Qb, Kb, Vtb, nullptr);

  k_attn_fused<<<1024, 512, 0, stream>>>(Qb, Kb, Vtb, mask, attn, ctx);

  k_gemm<2><<<dim3(64,8), 256, 0, stream>>>(ctx, wdt, wd_b, nullptr, nullptr,
                                            x, nullptr, nullptr, nullptr, out0);
  k_layernorm<<<NM, 256, 0, stream>>>(out0, gamma, beta);
}